// Round 4
// baseline (190.192 us; speedup 1.0000x reference)
//
#include <hip/hip_runtime.h>
#include <cstdint>

#define BLK 256
#define SPB 16                     // samples per K2 block
#define RS  9                      // xsi row stride in words (36 B)
#define ROWS 30
#define SS  (ROWS*RS)              // 270 words per sample
#define HDR 16                     // 64 B zero header
#define XS_INTS (HDR + SPB*SS)
#define YS_W 33                    // ysi words per sample (132 B, 125 used)
#define WPS 196                    // packed sign words per sample (784 B)
#define WPB (SPB*WPS)              // 3136 words per K2 block

// wsS layout (ints; floats stored via __int_as_float)
#define W0_OFF  0                  // 30: conv w bytes kc0..3 per (c*6+kr)
#define W1P_OFF 30                 // 15: conv w {kc4,kc5} of rows 2p,2p+1 per (c*3+p)
#define FC_OFF  45                 // 330: fc i8 sign words, o*33+w
#define CSC_OFF 375                // 5: conv folded scale
#define CBI_OFF 380                // 5: conv folded bias
#define FSC_OFF 385                // 10: fc folded scale
#define FBI_OFF 395                // 10: fc folded bias
#define WS_TOT  405

#if defined(__has_builtin)
# if __has_builtin(__builtin_amdgcn_sdot4)
#  define HAVE_SDOT4 1
# endif
#endif

__device__ __forceinline__ int dot4i8(int a, int b, int c) {
#ifdef HAVE_SDOT4
    return __builtin_amdgcn_sdot4(a, b, c, false);
#else
    int r = c;
    r += (((int)(a << 24)) >> 24) * (((int)(b << 24)) >> 24);
    r += (((int)(a << 16)) >> 24) * (((int)(b << 16)) >> 24);
    r += (((int)(a <<  8)) >> 24) * (((int)(b <<  8)) >> 24);
    r += (a >> 24) * (b >> 24);
    return r;
#endif
}

__device__ __forceinline__ int pack_sign4(float4 v) {
    int b0 = (v.x > 0.f) - (v.x < 0.f);
    int b1 = (v.y > 0.f) - (v.y < 0.f);
    int b2 = (v.z > 0.f) - (v.z < 0.f);
    int b3 = (v.w > 0.f) - (v.w < 0.f);
    return (b0 & 0xFF) | ((b1 & 0xFF) << 8) | ((b2 & 0xFF) << 16) | (b3 << 24);
}

__device__ __forceinline__ int sign8(float f) { return (f > 0.f) - (f < 0.f); }

// ===================== K1: pure-stream binarize (BW-bound) =====================
// 103 MB float -> 25.7 MB packed sign bytes in d_ws. Every load/store is
// lane-contiguous (16B loads, 4B stores). No LDS, no barriers, ~16 VGPRs.
__global__ __launch_bounds__(BLK)
void bnn_binarize(const float* __restrict__ x, int* __restrict__ sw)
{
    const int t0 = blockIdx.x * (4 * BLK) + threadIdx.x;   // float4-unit base
    const float4* x4 = (const float4*)x;
    float4 a = x4[t0];
    float4 b = x4[t0 + BLK];
    float4 c = x4[t0 + 2 * BLK];
    float4 d = x4[t0 + 3 * BLK];
    sw[t0]           = pack_sign4(a);
    sw[t0 + BLK]     = pack_sign4(b);
    sw[t0 + 2 * BLK] = pack_sign4(c);
    sw[t0 + 3 * BLK] = pack_sign4(d);
}

// ===================== K2: network from packed signs (tiny data) ===============
__global__ __launch_bounds__(BLK, 4)
void bnn_net(const int* __restrict__ sw,
             const float* __restrict__ conv_w, const float* __restrict__ conv_b,
             const float* __restrict__ bn2_g,  const float* __restrict__ bn2_b,
             const float* __restrict__ bn2_m,  const float* __restrict__ bn2_v,
             const float* __restrict__ fc_w,   const float* __restrict__ fc_b,
             const float* __restrict__ bn1_g,  const float* __restrict__ bn1_b,
             const float* __restrict__ bn1_m,  const float* __restrict__ bn1_v,
             float* __restrict__ out)
{
    __shared__ int   xsi[XS_INTS];
    __shared__ int   ysi[SPB * YS_W];
    __shared__ int   wsS[WS_TOT];
    __shared__ float zf[SPB * 10];

    const int tid = threadIdx.x;
    const int blk = blockIdx.x;

    // ---- issue sign loads first (12.5 KB/block, int4) ----
    const int4* sg4 = (const int4*)(sw + (size_t)blk * WPB);   // 784 int4
    int4 g0 = sg4[tid];
    int4 g1 = sg4[tid + 256];
    int4 g2 = sg4[tid + 512];
    int4 gr; const bool hasr = tid < (WPB / 4 - 768);          // 16 leftover
    if (hasr) gr = sg4[768 + tid];

    // ---- per-block weight build (small, L2-resident) ----
    if (tid < 30) {
        int c = tid / 6, kr = tid - c * 6;
        const float* wp = conv_w + c * 36 + kr * 6;
        uint32_t a = 0;
        #pragma unroll
        for (int k = 0; k < 4; k++) a |= (uint32_t)(sign8(wp[k]) & 0xFF) << (8 * k);
        wsS[W0_OFF + tid] = (int)a;
    } else if (tid >= 32 && tid < 47) {
        int i = tid - 32, c = i / 3, p = i - c * 3;
        const float* wp = conv_w + c * 36;
        uint32_t a = 0;
        a |= (uint32_t)(sign8(wp[(2*p)*6 + 4]) & 0xFF);
        a |= (uint32_t)(sign8(wp[(2*p)*6 + 5]) & 0xFF) << 8;
        a |= (uint32_t)(sign8(wp[(2*p+1)*6 + 4]) & 0xFF) << 16;
        a |= (uint32_t)(sign8(wp[(2*p+1)*6 + 5]) & 0xFF) << 24;
        wsS[W1P_OFF + i] = (int)a;
    } else if (tid >= 48 && tid < 53) {
        int c = tid - 48;
        float sc = bn2_g[c] / sqrtf(bn2_v[c] + 1e-5f);
        wsS[CSC_OFF + c] = __float_as_int(sc);
        wsS[CBI_OFF + c] = __float_as_int((conv_b[c] - bn2_m[c]) * sc + bn2_b[c]);
    } else if (tid >= 64 && tid < 74) {
        int o = tid - 64;
        float sc = bn1_g[o] / sqrtf(bn1_v[o] + 1e-5f);
        wsS[FSC_OFF + o] = __float_as_int(sc);
        wsS[FBI_OFF + o] = __float_as_int((fc_b[o] - bn1_m[o]) * sc + bn1_b[o]);
    }
    for (int i = tid; i < 330; i += BLK) {
        int o = i / 33, w = i - o * 33;
        uint32_t m = 0;
        #pragma unroll
        for (int k = 0; k < 4; k++) {
            int kk = w * 4 + k;
            if (kk < 125) m |= (uint32_t)(sign8(fc_w[o * 125 + kk]) & 0xFF) << (8 * k);
        }
        wsS[FC_OFF + i] = (int)m;
    }

    // ---- zero ONLY pad words of xsi (interior fully overwritten, disjoint) ----
    for (int i = tid; i < HDR + SPB * 74; i += BLK) {
        int idx;
        if (i < HDR) idx = i;
        else {
            int j = i - HDR, s = j / 74, k = j - s * 74;
            idx = HDR + s * SS + (k < 18 ? k : (2 + (k - 18) / 2) * RS + 7 + ((k - 18) & 1));
        }
        xsi[idx] = 0;
    }
    for (int i = tid; i < SPB * YS_W; i += BLK) ysi[i] = 0;

    // ---- scatter sign words into padded LDS layout ----
    {
        auto scat = [&](int j, int val) {
            int s = j / WPS, rem = j - s * WPS;
            int r = rem / 7, cq = rem - r * 7;
            xsi[HDR + s * SS + (r + 2) * RS + cq] = val;
        };
        int j0 = 4 * tid;
        scat(j0 + 0, g0.x); scat(j0 + 1, g0.y); scat(j0 + 2, g0.z); scat(j0 + 3, g0.w);
        int j1 = 4 * (tid + 256);
        scat(j1 + 0, g1.x); scat(j1 + 1, g1.y); scat(j1 + 2, g1.z); scat(j1 + 3, g1.w);
        int j2 = 4 * (tid + 512);
        scat(j2 + 0, g2.x); scat(j2 + 1, g2.y); scat(j2 + 2, g2.z); scat(j2 + 3, g2.w);
        if (hasr) {
            int j3 = 4 * (768 + tid);
            scat(j3 + 0, gr.x); scat(j3 + 1, gr.y); scat(j3 + 2, gr.z); scat(j3 + 3, gr.w);
        }
    }
    __syncthreads();

    // ---- conv: thread owns (s,pos), all 5 channels; window read ONCE ----
    {
        int w0[30], w1p[15]; float csc[5], cbi[5];
        #pragma unroll
        for (int i = 0; i < 30; i++) w0[i]  = wsS[W0_OFF + i];
        #pragma unroll
        for (int i = 0; i < 15; i++) w1p[i] = wsS[W1P_OFF + i];
        #pragma unroll
        for (int c = 0; c < 5; c++) {
            csc[c] = __int_as_float(wsS[CSC_OFF + c]);
            cbi[c] = __int_as_float(wsS[CBI_OFF + c]);
        }
        #pragma unroll
        for (int it = 0; it < 2; it++) {
            int j = tid + it * BLK;
            if (j < SPB * 25) {
                int s  = j / 25, pos = j - s * 25;
                int oh = pos / 5, ow  = pos - oh * 5;
                int q  = (6 * ow + 2) / 4 - 1;
                int sh = ((6 * ow + 2) & 3) * 8;
                int wi0 = HDR + s * SS + 54 * oh + q;
                uint32_t e0[6], e1[6];
                #pragma unroll
                for (int kr = 0; kr < 6; kr++) {
                    uint32_t a0 = (uint32_t)xsi[wi0 + 9 * kr];
                    uint32_t a1 = (uint32_t)xsi[wi0 + 9 * kr + 1];
                    uint64_t vv = ((((uint64_t)a1) << 32) | a0) >> sh;
                    e0[kr] = (uint32_t)vv;
                    e1[kr] = (uint32_t)(vv >> 32) & 0xFFFFu;
                }
                uint32_t e1p[3];
                #pragma unroll
                for (int p = 0; p < 3; p++) e1p[p] = e1[2*p] | (e1[2*p+1] << 16);
                #pragma unroll
                for (int c = 0; c < 5; c++) {
                    int acc = 0;
                    #pragma unroll
                    for (int kr = 0; kr < 6; kr++) acc = dot4i8((int)e0[kr], w0[c*6+kr], acc);
                    #pragma unroll
                    for (int p = 0; p < 3; p++)    acc = dot4i8((int)e1p[p], w1p[c*3+p], acc);
                    float yv = (float)acc * csc[c] + cbi[c];
                    ((signed char*)ysi)[s * (YS_W*4) + c * 25 + pos] = (signed char)sign8(yv);
                }
            }
        }
    }
    __syncthreads();

    // ---- FC: 160 threads, one (s,o) each ----
    if (tid < SPB * 10) {
        int s = tid / 10, o = tid - s * 10;
        int acc = 0;
        #pragma unroll
        for (int w = 0; w < 32; w++)
            acc = dot4i8(ysi[s * YS_W + w], wsS[FC_OFF + o * 33 + w], acc);
        zf[tid] = (float)acc * __int_as_float(wsS[FSC_OFF + o])
                             + __int_as_float(wsS[FBI_OFF + o]);
    }
    __syncthreads();

    // ---- log_softmax per sample ----
    if (tid < SPB) {
        float vv[10], mx = -1e30f;
        #pragma unroll
        for (int o = 0; o < 10; o++) { vv[o] = zf[tid * 10 + o]; mx = fmaxf(mx, vv[o]); }
        float l = 0.f;
        #pragma unroll
        for (int o = 0; o < 10; o++) l += __expf(vv[o] - mx);
        float lse = mx + __logf(l);
        #pragma unroll
        for (int o = 0; o < 10; o++) zf[tid * 10 + o] = vv[o] - lse;
    }
    __syncthreads();

    // ---- coalesced store ----
    for (int i = tid; i < SPB * 10; i += BLK)
        out[(size_t)blk * (SPB * 10) + i] = zf[i];
}

extern "C" void kernel_launch(void* const* d_in, const int* in_sizes, int n_in,
                              void* d_out, int out_size, void* d_ws, size_t ws_size,
                              hipStream_t stream)
{
    const float* xp     = (const float*)d_in[0];
    const float* conv_w = (const float*)d_in[1];
    const float* conv_b = (const float*)d_in[2];
    const float* bn2_g  = (const float*)d_in[3];
    const float* bn2_b  = (const float*)d_in[4];
    const float* bn2_m  = (const float*)d_in[5];
    const float* bn2_v  = (const float*)d_in[6];
    const float* fc_w   = (const float*)d_in[7];
    const float* fc_b   = (const float*)d_in[8];
    const float* bn1_g  = (const float*)d_in[9];
    const float* bn1_b  = (const float*)d_in[10];
    const float* bn1_m  = (const float*)d_in[11];
    const float* bn1_v  = (const float*)d_in[12];
    float* outp = (float*)d_out;
    int*   sw   = (int*)d_ws;

    const int B = in_sizes[0] / 784;            // 32768
    const int n4 = B * WPS;                     // total float4 / sign words
    const int grid1 = n4 / (4 * BLK);           // 6272
    const int grid2 = B / SPB;                  // 2048

    bnn_binarize<<<grid1, BLK, 0, stream>>>(xp, sw);
    bnn_net<<<grid2, BLK, 0, stream>>>(sw, conv_w, conv_b,
                                       bn2_g, bn2_b, bn2_m, bn2_v,
                                       fc_w, fc_b, bn1_g, bn1_b, bn1_m, bn1_v,
                                       outp);
}

// Round 5
// 178.165 us; speedup vs baseline: 1.0675x; 1.0675x over previous
//
#include <hip/hip_runtime.h>
#include <cstdint>

#define BLK 256
#define SPB 16                     // samples per block
#define HDRW 16                    // 64 B zero header (words) - absorbs top/left OOB reads
#define WPS 196                    // packed sign words per sample (raw 28x28 bytes)
#define XS_INTS (HDRW + SPB*WPS)   // 3152 words
#define YS_W 33                    // ysi words per sample (132 B, 125 used)
#define NQ 12                      // full staging rounds (3136 = 12*256 + 64)
#define NREM (SPB*WPS - NQ*BLK)    // 64

// wsS layout (ints; floats via __int_as_float)
#define W0_OFF  0                  // 30: conv w bytes kc0..3 per (c*6+kr)
#define W1P_OFF 30                 // 15: conv w {kc4,kc5} rows 2p,2p+1 per (c*3+p)
#define FC_OFF  45                 // 330: fc i8 sign words, o*33+w
#define CSC_OFF 375                // 5: conv folded scale
#define CBI_OFF 380                // 5: conv folded bias
#define FSC_OFF 385                // 10: fc folded scale
#define FBI_OFF 395                // 10: fc folded bias
#define WS_TOT  405

#if defined(__has_builtin)
# if __has_builtin(__builtin_amdgcn_sdot4)
#  define HAVE_SDOT4 1
# endif
#endif

__device__ __forceinline__ int dot4i8(int a, int b, int c) {
#ifdef HAVE_SDOT4
    return __builtin_amdgcn_sdot4(a, b, c, false);
#else
    int r = c;
    r += (((int)(a << 24)) >> 24) * (((int)(b << 24)) >> 24);
    r += (((int)(a << 16)) >> 24) * (((int)(b << 16)) >> 24);
    r += (((int)(a <<  8)) >> 24) * (((int)(b <<  8)) >> 24);
    r += (a >> 24) * (b >> 24);
    return r;
#endif
}

__device__ __forceinline__ int pack_sign4(float4 v) {
    int b0 = (v.x > 0.f) - (v.x < 0.f);
    int b1 = (v.y > 0.f) - (v.y < 0.f);
    int b2 = (v.z > 0.f) - (v.z < 0.f);
    int b3 = (v.w > 0.f) - (v.w < 0.f);
    return (b0 & 0xFF) | ((b1 & 0xFF) << 8) | ((b2 & 0xFF) << 16) | (b3 << 24);
}

__device__ __forceinline__ int sign8(float f) { return (f > 0.f) - (f < 0.f); }

__global__ __launch_bounds__(BLK, 2)
void bnn_fused(const float* __restrict__ x,
               const float* __restrict__ conv_w, const float* __restrict__ conv_b,
               const float* __restrict__ bn2_g,  const float* __restrict__ bn2_b,
               const float* __restrict__ bn2_m,  const float* __restrict__ bn2_v,
               const float* __restrict__ fc_w,   const float* __restrict__ fc_b,
               const float* __restrict__ bn1_g,  const float* __restrict__ bn1_b,
               const float* __restrict__ bn1_m,  const float* __restrict__ bn1_v,
               float* __restrict__ out)
{
    __shared__ int   xsi[XS_INTS];    // 64B zero header + raw packed signs
    __shared__ int   ysi[SPB * YS_W];
    __shared__ int   wsS[WS_TOT];
    __shared__ float zf[SPB * 10];

    const int tid = threadIdx.x;
    const int blk = blockIdx.x;

    // ---- issue all x loads first (lane-contiguous float4, stay in flight) ----
    const float4* xg = (const float4*)x + (size_t)blk * (SPB * WPS);
    float4 v[NQ]; float4 vr;
    #pragma unroll
    for (int k = 0; k < NQ; k++) v[k] = xg[tid + k * BLK];
    const bool hasr = tid < NREM;
    if (hasr) vr = xg[tid + NQ * BLK];

    // ---- per-block weight build (small, L2-resident) ----
    if (tid < 30) {
        int c = tid / 6, kr = tid - c * 6;
        const float* wp = conv_w + c * 36 + kr * 6;
        uint32_t a = 0;
        #pragma unroll
        for (int k = 0; k < 4; k++) a |= (uint32_t)(sign8(wp[k]) & 0xFF) << (8 * k);
        wsS[W0_OFF + tid] = (int)a;
    } else if (tid >= 32 && tid < 47) {
        int i = tid - 32, c = i / 3, p = i - c * 3;
        const float* wp = conv_w + c * 36;
        uint32_t a = 0;
        a |= (uint32_t)(sign8(wp[(2*p)*6 + 4]) & 0xFF);
        a |= (uint32_t)(sign8(wp[(2*p)*6 + 5]) & 0xFF) << 8;
        a |= (uint32_t)(sign8(wp[(2*p+1)*6 + 4]) & 0xFF) << 16;
        a |= (uint32_t)(sign8(wp[(2*p+1)*6 + 5]) & 0xFF) << 24;
        wsS[W1P_OFF + i] = (int)a;
    } else if (tid >= 48 && tid < 53) {
        int c = tid - 48;
        float sc = bn2_g[c] / sqrtf(bn2_v[c] + 1e-5f);
        wsS[CSC_OFF + c] = __float_as_int(sc);
        wsS[CBI_OFF + c] = __float_as_int((conv_b[c] - bn2_m[c]) * sc + bn2_b[c]);
    } else if (tid >= 64 && tid < 74) {
        int o = tid - 64;
        float sc = bn1_g[o] / sqrtf(bn1_v[o] + 1e-5f);
        wsS[FSC_OFF + o] = __float_as_int(sc);
        wsS[FBI_OFF + o] = __float_as_int((fc_b[o] - bn1_m[o]) * sc + bn1_b[o]);
    }
    for (int i = tid; i < 330; i += BLK) {
        int o = i / 33, w = i - o * 33;
        uint32_t m = 0;
        #pragma unroll
        for (int k = 0; k < 4; k++) {
            int kk = w * 4 + k;
            if (kk < 125) m |= (uint32_t)(sign8(fc_w[o * 125 + kk]) & 0xFF) << (8 * k);
        }
        wsS[FC_OFF + i] = (int)m;
    }

    // ---- zero header + ysi only (raw layout has no pad words) ----
    if (tid < HDRW) xsi[tid] = 0;
    for (int i = tid; i < SPB * YS_W; i += BLK) ysi[i] = 0;

    // ---- binarize + store: LINEAR addresses, zero address math ----
    #pragma unroll
    for (int k = 0; k < NQ; k++) xsi[HDRW + tid + k * BLK] = pack_sign4(v[k]);
    if (hasr) xsi[HDRW + tid + NQ * BLK] = pack_sign4(vr);
    __syncthreads();

    // ---- conv: thread owns (s,pos), all 5 channels; boundary via mask/redirect ----
    {
        int w0[30], w1p[15]; float csc[5], cbi[5];
        #pragma unroll
        for (int i = 0; i < 30; i++) w0[i]  = wsS[W0_OFF + i];
        #pragma unroll
        for (int i = 0; i < 15; i++) w1p[i] = wsS[W1P_OFF + i];
        #pragma unroll
        for (int c = 0; c < 5; c++) {
            csc[c] = __int_as_float(wsS[CSC_OFF + c]);
            cbi[c] = __int_as_float(wsS[CBI_OFF + c]);
        }
        #pragma unroll
        for (int it = 0; it < 2; it++) {
            int j = tid + it * BLK;
            if (j < SPB * 25) {
                int s  = j / 25, pos = j - s * 25;
                int oh = pos / 5, ow  = pos - oh * 5;
                // window row0 byte offset: s*784 + (6oh-2)*28 + (6ow-2)
                int rowb = s * 784 + 168 * oh + 6 * ow - 58;
                int q  = (64 + rowb) >> 2;              // word idx incl. header
                int sh = (rowb & 3) * 8;                // 16,0,16,0,16 across ow
                uint32_t emask = (ow == 0) ? 0xFFFF0000u : 0xFFFFFFFFu;
                uint32_t e0[6], e1[6];
                #pragma unroll
                for (int kr = 0; kr < 6; kr++) {
                    int a = q + 7 * kr;
                    if (kr < 2) a = (oh == 0) ? 0 : a;  // ih<0 rows -> zero header
                    uint32_t a0 = (uint32_t)xsi[a];
                    uint32_t a1 = (uint32_t)xsi[a + 1];
                    uint64_t vv = ((((uint64_t)a1) << 32) | a0) >> sh;
                    e0[kr] = (uint32_t)vv & emask;
                    e1[kr] = (uint32_t)(vv >> 32) & 0xFFFFu;
                }
                uint32_t e1p[3];
                #pragma unroll
                for (int p = 0; p < 3; p++) e1p[p] = e1[2*p] | (e1[2*p+1] << 16);
                #pragma unroll
                for (int c = 0; c < 5; c++) {
                    int acc = 0;
                    #pragma unroll
                    for (int kr = 0; kr < 6; kr++) acc = dot4i8((int)e0[kr], w0[c*6+kr], acc);
                    #pragma unroll
                    for (int p = 0; p < 3; p++)    acc = dot4i8((int)e1p[p], w1p[c*3+p], acc);
                    float yv = (float)acc * csc[c] + cbi[c];
                    // hardtanh preserves sign
                    ((signed char*)ysi)[s * (YS_W*4) + c * 25 + pos] = (signed char)sign8(yv);
                }
            }
        }
    }
    __syncthreads();

    // ---- FC: 160 threads, one (s,o) each ----
    if (tid < SPB * 10) {
        int s = tid / 10, o = tid - s * 10;
        int acc = 0;
        #pragma unroll
        for (int w = 0; w < 32; w++)
            acc = dot4i8(ysi[s * YS_W + w], wsS[FC_OFF + o * 33 + w], acc);
        zf[tid] = (float)acc * __int_as_float(wsS[FSC_OFF + o])
                             + __int_as_float(wsS[FBI_OFF + o]);
    }
    __syncthreads();

    // ---- log_softmax per sample ----
    if (tid < SPB) {
        float vv[10], mx = -1e30f;
        #pragma unroll
        for (int o = 0; o < 10; o++) { vv[o] = zf[tid * 10 + o]; mx = fmaxf(mx, vv[o]); }
        float l = 0.f;
        #pragma unroll
        for (int o = 0; o < 10; o++) l += __expf(vv[o] - mx);
        float lse = mx + __logf(l);
        #pragma unroll
        for (int o = 0; o < 10; o++) zf[tid * 10 + o] = vv[o] - lse;
    }
    __syncthreads();

    // ---- coalesced store ----
    for (int i = tid; i < SPB * 10; i += BLK)
        out[(size_t)blk * (SPB * 10) + i] = zf[i];
}

extern "C" void kernel_launch(void* const* d_in, const int* in_sizes, int n_in,
                              void* d_out, int out_size, void* d_ws, size_t ws_size,
                              hipStream_t stream)
{
    const float* xp     = (const float*)d_in[0];
    const float* conv_w = (const float*)d_in[1];
    const float* conv_b = (const float*)d_in[2];
    const float* bn2_g  = (const float*)d_in[3];
    const float* bn2_b  = (const float*)d_in[4];
    const float* bn2_m  = (const float*)d_in[5];
    const float* bn2_v  = (const float*)d_in[6];
    const float* fc_w   = (const float*)d_in[7];
    const float* fc_b   = (const float*)d_in[8];
    const float* bn1_g  = (const float*)d_in[9];
    const float* bn1_b  = (const float*)d_in[10];
    const float* bn1_m  = (const float*)d_in[11];
    const float* bn1_v  = (const float*)d_in[12];
    float* outp = (float*)d_out;

    const int B = in_sizes[0] / 784;      // 32768
    const int grid = B / SPB;             // 2048
    bnn_fused<<<grid, BLK, 0, stream>>>(xp, conv_w, conv_b,
                                        bn2_g, bn2_b, bn2_m, bn2_v,
                                        fc_w, fc_b, bn1_g, bn1_b, bn1_m, bn1_v,
                                        outp);
}